// Round 2
// baseline (942.776 us; speedup 1.0000x reference)
//
#include <hip/hip_runtime.h>

#define H_IMG 64
#define W_IMG 64
#define N_NODE 1024
#define HID 90
#define HIDP 92   // padded K so rows are 16B-aligned and divisible by 4

struct alignas(16) SMem {
    float W1T[90 * 8];    // [j][e], e padded to 8 (e=7 is zero)
    float W2T[90 * HIDP]; // [j][k], k padded to 92 (k=90,91 zero)
    float B1[90];
    float B2[90];
    float W3[90];
    float B3;
};

__device__ __forceinline__ float elu_f(float x) {
    // x>0: fmax=x, exp(0)-1=0 -> x ; x<=0: 0 + exp(x)-1
    return fmaxf(x, 0.f) + (__expf(fminf(x, 0.f)) - 1.f);
}

__device__ __forceinline__ void compute_h1(const SMem& sm,
                                           const float* __restrict__ x,
                                           const float* __restrict__ controls,
                                           const int* __restrict__ inputs_list,
                                           const int* __restrict__ control_list,
                                           int row, float* h1)
{
    const int b = row >> 10;          // row / N_NODE
    const int n = row & 1023;         // row % N_NODE
    const int ph = n >> 5, pw = n & 31;

    const float* xp = x + (size_t)b * (H_IMG * W_IMG) + (ph * 2) * W_IMG + pw * 2;
    const float2 pA = *(const float2*)xp;            // (kh=0,kw=0),(kh=0,kw=1)
    const float2 pB = *(const float2*)(xp + W_IMG);  // (kh=1,kw=0),(kh=1,kw=1)

    const int4 il = *(const int4*)(inputs_list + n * 4);
    const int cl0 = control_list[n * 3 + 0];
    const int cl1 = control_list[n * 3 + 1];
    const int cl2 = control_list[n * 3 + 2];
    const float c0 = controls[n * 3 + 0];
    const float c1 = controls[n * 3 + 1];
    const float c2 = controls[n * 3 + 2];

    // Branchless inverse-scatter: E[e] for e=0..6 (compile-time indices -> VGPRs)
    float E[8];
    E[7] = 0.f;
#pragma unroll
    for (int e = 0; e < 7; ++e) {
        float v = 0.f;
        v = (il.x == e) ? pA.x : v;
        v = (il.y == e) ? pA.y : v;
        v = (il.z == e) ? pB.x : v;
        v = (il.w == e) ? pB.y : v;
        v = (cl0 == e) ? c0 : v;
        v = (cl1 == e) ? c1 : v;
        v = (cl2 == e) ? c2 : v;
        E[e] = v;
    }

    // h1[j] = elu(b1[j] + sum_e E[e]*W1[e][j]) ; fully unrolled so h1 stays in regs
#pragma unroll
    for (int j = 0; j < 90; ++j) {
        const float4 w0 = *(const float4*)&sm.W1T[j * 8 + 0];
        const float4 w1 = *(const float4*)&sm.W1T[j * 8 + 4];
        float a = sm.B1[j];
        a += E[0] * w0.x + E[1] * w0.y + E[2] * w0.z + E[3] * w0.w;
        a += E[4] * w1.x + E[5] * w1.y + E[6] * w1.z; // E[7]*w1.w == 0
        h1[j] = elu_f(a);
    }
    h1[90] = 0.f;
    h1[91] = 0.f;
}

__global__ __launch_bounds__(256, 2)
void dnpu_lrf_kernel(const float* __restrict__ x,
                     const float* __restrict__ controls,
                     const float* __restrict__ W1, const float* __restrict__ b1,
                     const float* __restrict__ W2, const float* __restrict__ b2,
                     const float* __restrict__ W3, const float* __restrict__ b3,
                     const int* __restrict__ inputs_list,
                     const int* __restrict__ control_list,
                     float* __restrict__ out)
{
    __shared__ SMem sm;
    const int t = threadIdx.x;

    // ---- stage weights into LDS (transposed; pads zeroed) ----
    for (int idx = t; idx < 90 * 90; idx += 256) {
        const int k = idx / 90;            // W2 row (input dim)
        const int j = idx - k * 90;        // W2 col (output dim)
        sm.W2T[j * HIDP + k] = W2[idx];
    }
    for (int idx = t; idx < 7 * 90; idx += 256) {
        const int e = idx / 90;
        const int j = idx - e * 90;
        sm.W1T[j * 8 + e] = W1[idx];
    }
    if (t < 90) {
        sm.W2T[t * HIDP + 90] = 0.f;
        sm.W2T[t * HIDP + 91] = 0.f;
        sm.W1T[t * 8 + 7] = 0.f;
        sm.B1[t] = b1[t];
        sm.B2[t] = b2[t];
        sm.W3[t] = W3[t];
    }
    if (t == 0) sm.B3 = b3[0];
    __syncthreads();

    // ---- two rows per thread (register blocking over the shared W2 reads) ----
    const int base = blockIdx.x * 512;
    float h1a[HIDP];
    float h1b[HIDP];
    compute_h1(sm, x, controls, inputs_list, control_list, base + t, h1a);
    compute_h1(sm, x, controls, inputs_list, control_list, base + 256 + t, h1b);

    float acc0 = 0.f, acc1 = 0.f;
    for (int j = 0; j < 90; ++j) {
        const float* wr = &sm.W2T[j * HIDP];
        float a0 = sm.B2[j];
        float a1 = a0;
#pragma unroll
        for (int k = 0; k < HIDP; k += 4) {
            const float4 w = *(const float4*)(wr + k);
            a0 += h1a[k] * w.x + h1a[k + 1] * w.y + h1a[k + 2] * w.z + h1a[k + 3] * w.w;
            a1 += h1b[k] * w.x + h1b[k + 1] * w.y + h1b[k + 2] * w.z + h1b[k + 3] * w.w;
        }
        const float w3 = sm.W3[j];
        acc0 += elu_f(a0) * w3;
        acc1 += elu_f(a1) * w3;
    }

    out[base + t]       = acc0 + sm.B3;
    out[base + 256 + t] = acc1 + sm.B3;
}

extern "C" void kernel_launch(void* const* d_in, const int* in_sizes, int n_in,
                              void* d_out, int out_size, void* d_ws, size_t ws_size,
                              hipStream_t stream)
{
    const float* x            = (const float*)d_in[0];
    const float* controls     = (const float*)d_in[1];
    const float* W1           = (const float*)d_in[2];
    const float* b1           = (const float*)d_in[3];
    const float* W2           = (const float*)d_in[4];
    const float* b2           = (const float*)d_in[5];
    const float* W3           = (const float*)d_in[6];
    const float* b3           = (const float*)d_in[7];
    const int* inputs_list    = (const int*)d_in[8];
    const int* control_list   = (const int*)d_in[9];
    float* out = (float*)d_out;

    // 1,048,576 rows / 512 rows per block
    dim3 grid(2048), block(256);
    hipLaunchKernelGGL(dnpu_lrf_kernel, grid, block, 0, stream,
                       x, controls, W1, b1, W2, b2, W3, b3,
                       inputs_list, control_list, out);
}

// Round 5
// 275.230 us; speedup vs baseline: 3.4254x; 3.4254x over previous
//
#include <hip/hip_runtime.h>

// DNPU local-receptive-field surrogate: 1,048,576 rows of (gather -> 7->90->90->1 MLP).
// Strategy: one row per thread; loop-swapped layer1/layer2 so the only persistent
// per-thread array is h2[90] (static indices only -> stays in VGPRs); all weights
// read as wave-uniform scalar loads from a prepped, padded workspace (no LDS).

#define HID 90

// Workspace layout (floats):
//   W2P : [0, 8640)    90 rows x 96 cols (col j, pad 90..95 = 0), rows 64B-aligned
//   W1P : [8640, 9360) 90 rows x 8  (e=0..6 -> W1[e][k]; e=7 -> b1[k])
//   B2P : [9360, 9456) b2 (pad 0)
//   W3P : [9456, 9552) W3 (pad 0)
//   B3  : [9552]
#define WS_W2P 0
#define WS_W1P 8640
#define WS_B2P 9360
#define WS_W3P 9456
#define WS_B3  9552
#define WS_TOT 9553

__global__ void prep_kernel(const float* __restrict__ W1, const float* __restrict__ b1,
                            const float* __restrict__ W2, const float* __restrict__ b2,
                            const float* __restrict__ W3, const float* __restrict__ b3,
                            float* __restrict__ wsf)
{
    int i = blockIdx.x * blockDim.x + threadIdx.x;
    for (; i < WS_TOT; i += gridDim.x * blockDim.x) {
        float v;
        if (i < WS_W1P) {                    // W2P[k][j]
            const int k = i / 96, j = i - k * 96;
            v = (j < HID) ? W2[k * HID + j] : 0.f;
        } else if (i < WS_B2P) {             // W1P[k][e]
            const int r = i - WS_W1P, k = r >> 3, e = r & 7;
            v = (e < 7) ? W1[e * HID + k] : b1[k];
        } else if (i < WS_W3P) {
            const int j = i - WS_B2P;
            v = (j < HID) ? b2[j] : 0.f;
        } else if (i < WS_B3) {
            const int j = i - WS_W3P;
            v = (j < HID) ? W3[j] : 0.f;
        } else {
            v = b3[0];
        }
        wsf[i] = v;
    }
}

__device__ __forceinline__ float elu_f(float x) {
    // x>0: x + (exp(0)-1)=x ; x<=0: 0 + exp(x)-1
    return fmaxf(x, 0.f) + (__expf(fminf(x, 0.f)) - 1.f);
}

__global__ __launch_bounds__(256, 4)
void dnpu_main(const float* __restrict__ x,
               const float* __restrict__ controls,
               const int* __restrict__ inputs_list,
               const int* __restrict__ control_list,
               const float* __restrict__ wsf,
               float* __restrict__ out)
{
    const int t   = threadIdx.x;
    const int row = blockIdx.x * 256 + t;       // exactly B*N rows, no guard needed
    const int b   = row >> 10;                  // batch
    const int n   = row & 1023;                 // node
    const int ph  = n >> 5, pw = n & 31;

    // --- gather the 2x2 patch (coalesced float2 pairs) ---
    const float* xp = x + ((size_t)b << 12) + (ph * 2) * 64 + pw * 2;
    const float2 pA = *(const float2*)xp;        // (kh0,kw0),(kh0,kw1)
    const float2 pB = *(const float2*)(xp + 64); // (kh1,kw0),(kh1,kw1)

    const int4 il  = *(const int4*)(inputs_list + (n << 2));
    const int  cl0 = control_list[n * 3 + 0];
    const int  cl1 = control_list[n * 3 + 1];
    const int  cl2 = control_list[n * 3 + 2];
    const float c0 = controls[n * 3 + 0];
    const float c1 = controls[n * 3 + 1];
    const float c2 = controls[n * 3 + 2];

    // --- branchless inverse scatter into E[0..6]; E[7]=1 pairs with b1 in W1P ---
    float E[8];
    E[7] = 1.0f;
#pragma unroll
    for (int e = 0; e < 7; ++e) {
        float v = 0.f;
        v = (il.x == e) ? pA.x : v;
        v = (il.y == e) ? pA.y : v;
        v = (il.z == e) ? pB.x : v;
        v = (il.w == e) ? pB.y : v;
        v = (cl0 == e) ? c0 : v;
        v = (cl1 == e) ? c1 : v;
        v = (cl2 == e) ? c2 : v;
        E[e] = v;
    }

    const float* W2P = wsf + WS_W2P;
    const float* W1P = wsf + WS_W1P;
    const float* B2P = wsf + WS_B2P;
    const float* W3P = wsf + WS_W3P;

    // --- layer-2 accumulators; ONLY static indices touch this array ---
    float h2[HID];
#pragma unroll
    for (int j = 0; j < HID; ++j) h2[j] = B2P[j];

    // --- fused layer1 + layer2, loop-swapped over k ---
    for (int k = 0; k < HID; ++k) {
        const float* w1r = W1P + (k << 3);   // uniform -> scalar loads
        float pre = 0.f;
#pragma unroll
        for (int e = 0; e < 8; ++e) pre = __builtin_fmaf(E[e], w1r[e], pre);
        const float h1k = elu_f(pre);

        const float* w2r = W2P + k * 96;     // 64B-aligned row, uniform -> s_load_dwordx16
#pragma unroll
        for (int j = 0; j < HID; ++j) h2[j] = __builtin_fmaf(h1k, w2r[j], h2[j]);
    }

    // --- layer 3 ---
    float acc = 0.f;
#pragma unroll
    for (int j = 0; j < HID; ++j) acc = __builtin_fmaf(elu_f(h2[j]), W3P[j], acc);

    out[row] = acc + wsf[WS_B3];
}

extern "C" void kernel_launch(void* const* d_in, const int* in_sizes, int n_in,
                              void* d_out, int out_size, void* d_ws, size_t ws_size,
                              hipStream_t stream)
{
    const float* x          = (const float*)d_in[0];
    const float* controls   = (const float*)d_in[1];
    const float* W1         = (const float*)d_in[2];
    const float* b1         = (const float*)d_in[3];
    const float* W2         = (const float*)d_in[4];
    const float* b2         = (const float*)d_in[5];
    const float* W3         = (const float*)d_in[6];
    const float* b3         = (const float*)d_in[7];
    const int* inputs_list  = (const int*)d_in[8];
    const int* control_list = (const int*)d_in[9];
    float* out = (float*)d_out;
    float* wsf = (float*)d_ws;

    hipLaunchKernelGGL(prep_kernel, dim3(32), dim3(256), 0, stream,
                       W1, b1, W2, b2, W3, b3, wsf);
    hipLaunchKernelGGL(dnpu_main, dim3(4096), dim3(256), 0, stream,
                       x, controls, inputs_list, control_list, wsf, out);
}

// Round 8
// 177.192 us; speedup vs baseline: 5.3207x; 1.5533x over previous
//
#include <hip/hip_runtime.h>
#include <stdint.h>

// DNPU LRF: 1,048,576 rows of (gather -> 7->90->90->1 MLP).
// Layer1 fp32 VALU (scalar-load W1), layer2 = fp16 MFMA 16x16x32 (81% of FLOPs
// on the matrix pipe), layer3 fp32 VALU on the C-fragment layout + shfl reduce.

#define HID 90

typedef float  f32x4 __attribute__((ext_vector_type(4)));
typedef _Float16 f16x8 __attribute__((ext_vector_type(8)));

// Workspace layout (float units unless noted):
//   W1P : [0,720)    90 rows x 8: [k][e], e=0..6 -> W1[e][k], e=7 -> b1[k]
//   B2V : [720,816)  b2 padded to 96 (pad=0)
//   W3V : [816,912)  W3 padded to 96 (pad=0)
//   B3  : [912]      b3 ; [913,928) pad
//   W2F : [928, 928+4608) as fp16: 18 fragments (ks=0..2, jt=0..5) x 64 lanes x 8
//         halves, element (f,l,i) = W2[ks*32+8*(l>>4)+i][jt*16+(l&15)] (0 if OOB)
#define WS_W1P 0
#define WS_B2V 720
#define WS_W3V 816
#define WS_B3  912
#define WS_W2F 928
#define WS_TOT_ELEMS (928 + 9216)   // 928 floats + 9216 halves

__global__ void prep_kernel(const float* __restrict__ W1, const float* __restrict__ b1,
                            const float* __restrict__ W2, const float* __restrict__ b2,
                            const float* __restrict__ W3, const float* __restrict__ b3,
                            float* __restrict__ wsf)
{
    _Float16* w2f = (_Float16*)(wsf + WS_W2F);
    for (int i = blockIdx.x * blockDim.x + threadIdx.x; i < WS_TOT_ELEMS;
         i += gridDim.x * blockDim.x) {
        if (i < 928) {
            float v = 0.f;
            if (i < WS_B2V) {                       // W1P[k][e]
                const int k = i >> 3, e = i & 7;
                v = (e < 7) ? W1[e * HID + k] : b1[k];
            } else if (i < WS_W3V) {
                const int j = i - WS_B2V; v = (j < HID) ? b2[j] : 0.f;
            } else if (i < WS_B3) {
                const int j = i - WS_W3V; v = (j < HID) ? W3[j] : 0.f;
            } else if (i == WS_B3) {
                v = b3[0];
            }                                        // 913..927 -> 0
            wsf[i] = v;
        } else {                                     // W2 fragment-order fp16
            const int e  = i - 928;
            const int f  = e >> 9;                   // fragment 0..17
            const int r  = e & 511;
            const int l  = r >> 3, ii = r & 7;       // lane, elem
            const int ks = f / 6, jt = f - ks * 6;
            const int k  = ks * 32 + ((l >> 4) << 3) + ii;
            const int j  = jt * 16 + (l & 15);
            const float v = (k < HID && j < HID) ? W2[k * HID + j] : 0.f;
            w2f[e] = (_Float16)v;
        }
    }
}

__device__ __forceinline__ float elu_f(float x) {
    return fmaxf(x, 0.f) + (__expf(fminf(x, 0.f)) - 1.f);
}

__device__ __forceinline__ uint32_t pk_f16(float a, float b) {
    auto r = __builtin_amdgcn_cvt_pkrtz(a, b);      // __fp16 ext_vector_type(2)
    return __builtin_bit_cast(uint32_t, r);
}

__global__ __launch_bounds__(256, 2)
void dnpu_main(const float* __restrict__ x,
               const float* __restrict__ controls,
               const int* __restrict__ inputs_list,
               const int* __restrict__ control_list,
               const float* __restrict__ wsf,
               float* __restrict__ out)
{
    __shared__ _Float16 Hs[256 * 104];   // h1 tile, 104-stride (2-way-conflict, 16B-aligned)

    const int t   = threadIdx.x;
    const int row = blockIdx.x * 256 + t;
    const int b   = row >> 10;
    const int n   = row & 1023;
    const int ph  = n >> 5, pw = n & 31;

    // ---- gather 2x2 patch + electrode assembly (branchless inverse scatter) ----
    const float* xp = x + ((size_t)b << 12) + (ph * 2) * 64 + pw * 2;
    const float2 pA = *(const float2*)xp;
    const float2 pB = *(const float2*)(xp + 64);

    const int4 il  = *(const int4*)(inputs_list + (n << 2));
    const int  cl0 = control_list[n * 3 + 0];
    const int  cl1 = control_list[n * 3 + 1];
    const int  cl2 = control_list[n * 3 + 2];
    const float c0 = controls[n * 3 + 0];
    const float c1 = controls[n * 3 + 1];
    const float c2 = controls[n * 3 + 2];

    float E[8];
    E[7] = 1.0f;                          // pairs with b1 folded into W1P[k][7]
#pragma unroll
    for (int e = 0; e < 7; ++e) {
        float v = 0.f;
        v = (il.x == e) ? pA.x : v;
        v = (il.y == e) ? pA.y : v;
        v = (il.z == e) ? pB.x : v;
        v = (il.w == e) ? pB.y : v;
        v = (cl0 == e) ? c0 : v;
        v = (cl1 == e) ? c1 : v;
        v = (cl2 == e) ? c2 : v;
        E[e] = v;
    }

    // ---- layer 1: fp32, two outputs per iter (ILP), pack fp16 -> LDS ----
    const float* W1P = wsf + WS_W1P;
    _Float16* hrow = &Hs[t * 104];
    for (int k = 0; k < HID; k += 2) {
        const float* wA = W1P + (k << 3);
        float pa0 = 0.f, pa1 = 0.f, pb0 = 0.f, pb1 = 0.f;
#pragma unroll
        for (int e = 0; e < 8; e += 2) {
            pa0 = __builtin_fmaf(E[e],     wA[e],     pa0);
            pa1 = __builtin_fmaf(E[e + 1], wA[e + 1], pa1);
            pb0 = __builtin_fmaf(E[e],     wA[e + 8], pb0);
            pb1 = __builtin_fmaf(E[e + 1], wA[e + 9], pb1);
        }
        const float ha = elu_f(pa0 + pa1);
        const float hb = elu_f(pb0 + pb1);
        *(uint32_t*)&hrow[k] = pk_f16(ha, hb);      // k even -> 4B-aligned
    }
    *(uint32_t*)&hrow[90] = 0u;
    *(uint32_t*)&hrow[92] = 0u;
    *(uint32_t*)&hrow[94] = 0u;

    // ---- per-lane constants for the MFMA/epilogue phase ----
    const int w  = t >> 6;
    const int l  = t & 63;
    const int lj = l & 15;        // C/D col within tile ; A row within tile
    const int lg = l >> 4;        // k-group ; C/D row-group
    const float* B2V = wsf + WS_B2V;
    const float* W3V = wsf + WS_W3V;
    float b2j[6], w3j[6];
#pragma unroll
    for (int jt = 0; jt < 6; ++jt) {
        b2j[jt] = B2V[jt * 16 + lj];
        w3j[jt] = W3V[jt * 16 + lj];
    }
    const float B3v = wsf[WS_B3];

    f32x4 acc[4][6];
#pragma unroll
    for (int rt = 0; rt < 4; ++rt)
#pragma unroll
        for (int jt = 0; jt < 6; ++jt)
            acc[rt][jt] = (f32x4){b2j[jt], b2j[jt], b2j[jt], b2j[jt]};

    __syncthreads();

    // ---- layer 2: fp16 MFMA 16x16x32 ; wave w owns rows w*64 .. w*64+63 ----
    const _Float16* w2f = (const _Float16*)(wsf + WS_W2F);
#pragma unroll
    for (int ks = 0; ks < 3; ++ks) {
        f16x8 bfr[6];
#pragma unroll
        for (int jt = 0; jt < 6; ++jt)
            bfr[jt] = *(const f16x8*)(w2f + (((ks * 6 + jt) * 64 + l) << 3));
        f16x8 afr[4];
#pragma unroll
        for (int rt = 0; rt < 4; ++rt)
            afr[rt] = *(const f16x8*)&Hs[(w * 64 + rt * 16 + lj) * 104 + ks * 32 + 8 * lg];
#pragma unroll
        for (int rt = 0; rt < 4; ++rt)
#pragma unroll
            for (int jt = 0; jt < 6; ++jt)
                acc[rt][jt] = __builtin_amdgcn_mfma_f32_16x16x32_f16(
                    afr[rt], bfr[jt], acc[rt][jt], 0, 0, 0);
    }

    // ---- layer 3: elu + W3 on C layout (col=lj, row=4*lg+reg), shfl-reduce ----
    const int rowbase = blockIdx.x * 256 + w * 64;
#pragma unroll
    for (int rt = 0; rt < 4; ++rt) {
        float p0 = 0.f, p1 = 0.f, p2 = 0.f, p3 = 0.f;
#pragma unroll
        for (int jt = 0; jt < 6; ++jt) {
            p0 += elu_f(acc[rt][jt][0]) * w3j[jt];
            p1 += elu_f(acc[rt][jt][1]) * w3j[jt];
            p2 += elu_f(acc[rt][jt][2]) * w3j[jt];
            p3 += elu_f(acc[rt][jt][3]) * w3j[jt];
        }
#pragma unroll
        for (int mask = 1; mask < 16; mask <<= 1) {
            p0 += __shfl_xor(p0, mask);
            p1 += __shfl_xor(p1, mask);
            p2 += __shfl_xor(p2, mask);
            p3 += __shfl_xor(p3, mask);
        }
        if (lj < 4) {
            const float v = (lj == 0) ? p0 : (lj == 1) ? p1 : (lj == 2) ? p2 : p3;
            out[rowbase + rt * 16 + 4 * lg + lj] = v + B3v;
        }
    }
}

extern "C" void kernel_launch(void* const* d_in, const int* in_sizes, int n_in,
                              void* d_out, int out_size, void* d_ws, size_t ws_size,
                              hipStream_t stream)
{
    const float* x          = (const float*)d_in[0];
    const float* controls   = (const float*)d_in[1];
    const float* W1         = (const float*)d_in[2];
    const float* b1         = (const float*)d_in[3];
    const float* W2         = (const float*)d_in[4];
    const float* b2         = (const float*)d_in[5];
    const float* W3         = (const float*)d_in[6];
    const float* b3         = (const float*)d_in[7];
    const int* inputs_list  = (const int*)d_in[8];
    const int* control_list = (const int*)d_in[9];
    float* out = (float*)d_out;
    float* wsf = (float*)d_ws;

    hipLaunchKernelGGL(prep_kernel, dim3(40), dim3(256), 0, stream,
                       W1, b1, W2, b2, W3, b3, wsf);
    hipLaunchKernelGGL(dnpu_main, dim3(4096), dim3(256), 0, stream,
                       x, controls, inputs_list, control_list, wsf, out);
}

// Round 11
// 166.073 us; speedup vs baseline: 5.6769x; 1.0669x over previous
//
#include <hip/hip_runtime.h>
#include <stdint.h>

// DNPU LRF: 1,048,576 rows of (gather -> 7->90->90->1 MLP).
// Layer1 fp32 VALU -> packed fp16 written DIRECTLY in MFMA A-fragment order
// (12 conflict-free ds_write_b128/thread, no __syncthreads: waves self-contained).
// Layer2 = fp16 MFMA 16x16x32. Layer3 fp32 VALU on C layout + 16-lane shfl reduce.

#define HID 90

typedef float  f32x4 __attribute__((ext_vector_type(4)));
typedef _Float16 f16x8 __attribute__((ext_vector_type(8)));

// Workspace layout (float units unless noted):
//   W1P : [0,720)    90 rows x 8: [k][e], e=0..6 -> W1[e][k], e=7 -> b1[k]
//   B2V : [720,816)  b2 padded to 96 (pad=0)
//   W3V : [816,912)  W3 padded to 96 (pad=0)
//   B3  : [912]      b3 ; [913,928) pad
//   W2F : [928, 928+4608) as fp16: 18 fragments (ks=0..2, jt=0..5) x 64 lanes x 8
//         halves, element (f,l,i) = W2[ks*32+8*(l>>4)+i][jt*16+(l&15)] (0 if OOB)
#define WS_W1P 0
#define WS_B2V 720
#define WS_W3V 816
#define WS_B3  912
#define WS_W2F 928
#define WS_TOT_ELEMS (928 + 9216)   // 928 floats + 9216 halves

__global__ void prep_kernel(const float* __restrict__ W1, const float* __restrict__ b1,
                            const float* __restrict__ W2, const float* __restrict__ b2,
                            const float* __restrict__ W3, const float* __restrict__ b3,
                            float* __restrict__ wsf)
{
    _Float16* w2f = (_Float16*)(wsf + WS_W2F);
    for (int i = blockIdx.x * blockDim.x + threadIdx.x; i < WS_TOT_ELEMS;
         i += gridDim.x * blockDim.x) {
        if (i < 928) {
            float v = 0.f;
            if (i < WS_B2V) {                       // W1P[k][e]
                const int k = i >> 3, e = i & 7;
                v = (e < 7) ? W1[e * HID + k] : b1[k];
            } else if (i < WS_W3V) {
                const int j = i - WS_B2V; v = (j < HID) ? b2[j] : 0.f;
            } else if (i < WS_B3) {
                const int j = i - WS_W3V; v = (j < HID) ? W3[j] : 0.f;
            } else if (i == WS_B3) {
                v = b3[0];
            }                                        // 913..927 -> 0
            wsf[i] = v;
        } else {                                     // W2 fragment-order fp16
            const int e  = i - 928;
            const int f  = e >> 9;                   // fragment 0..17
            const int r  = e & 511;
            const int l  = r >> 3, ii = r & 7;       // lane, elem
            const int ks = f / 6, jt = f - ks * 6;
            const int k  = ks * 32 + ((l >> 4) << 3) + ii;
            const int j  = jt * 16 + (l & 15);
            const float v = (k < HID && j < HID) ? W2[k * HID + j] : 0.f;
            w2f[e] = (_Float16)v;
        }
    }
}

__device__ __forceinline__ float elu_f(float x) {
    return fmaxf(x, 0.f) + (__expf(fminf(x, 0.f)) - 1.f);
}

__device__ __forceinline__ uint32_t pk_f16(float a, float b) {
    auto r = __builtin_amdgcn_cvt_pkrtz(a, b);      // __fp16 ext_vector_type(2)
    return __builtin_bit_cast(uint32_t, r);
}

__global__ __launch_bounds__(256, 2)
void dnpu_main(const float* __restrict__ x,
               const float* __restrict__ controls,
               const int* __restrict__ inputs_list,
               const int* __restrict__ control_list,
               const float* __restrict__ wsf,
               float* __restrict__ out)
{
    // h1 in A-fragment order: [wave][ks][rt][lane][8 halves] = 48 KiB
    __shared__ alignas(16) _Float16 Hs[4 * 3 * 4 * 64 * 8];

    const int t    = threadIdx.x;
    const int row  = blockIdx.x * 256 + t;
    const int b    = row >> 10;
    const int n    = row & 1023;
    const int ph   = n >> 5, pw = n & 31;
    const int w    = t >> 6;
    const int lane = t & 63;
    const int rt_w = lane >> 4;   // this thread's row-tile (as producer)
    const int lj   = lane & 15;   // A-row / C-col within tile

    // ---- gather 2x2 patch + electrode assembly (branchless inverse scatter) ----
    const float* xp = x + ((size_t)b << 12) + (ph * 2) * 64 + pw * 2;
    const float2 pA = *(const float2*)xp;
    const float2 pB = *(const float2*)(xp + 64);

    const int4 il  = *(const int4*)(inputs_list + (n << 2));
    const int  cl0 = control_list[n * 3 + 0];
    const int  cl1 = control_list[n * 3 + 1];
    const int  cl2 = control_list[n * 3 + 2];
    const float c0 = controls[n * 3 + 0];
    const float c1 = controls[n * 3 + 1];
    const float c2 = controls[n * 3 + 2];

    float E[8];
    E[7] = 1.0f;                          // pairs with b1 folded into W1P[k][7]
#pragma unroll
    for (int e = 0; e < 7; ++e) {
        float v = 0.f;
        v = (il.x == e) ? pA.x : v;
        v = (il.y == e) ? pA.y : v;
        v = (il.z == e) ? pB.x : v;
        v = (il.w == e) ? pB.y : v;
        v = (cl0 == e) ? c0 : v;
        v = (cl1 == e) ? c1 : v;
        v = (cl2 == e) ? c2 : v;
        E[e] = v;
    }

    // ---- layer 1: fp32 pairs -> packed fp16, ds_write_b128 per 8-wide k-group ----
    const float* W1P = wsf + WS_W1P;
#pragma unroll
    for (int ks = 0; ks < 3; ++ks) {
#pragma unroll
        for (int lg = 0; lg < 4; ++lg) {
            uint32_t pk4[4];
#pragma unroll
            for (int p = 0; p < 4; ++p) {
                const int k = ks * 32 + lg * 8 + p * 2;
                if (k < HID) {
                    const float* wA = W1P + (k << 3);
                    float pa0 = 0.f, pa1 = 0.f, pb0 = 0.f, pb1 = 0.f;
#pragma unroll
                    for (int e = 0; e < 8; e += 2) {
                        pa0 = __builtin_fmaf(E[e],     wA[e],     pa0);
                        pa1 = __builtin_fmaf(E[e + 1], wA[e + 1], pa1);
                        pb0 = __builtin_fmaf(E[e],     wA[e + 8], pb0);
                        pb1 = __builtin_fmaf(E[e + 1], wA[e + 9], pb1);
                    }
                    pk4[p] = pk_f16(elu_f(pa0 + pa1), elu_f(pb0 + pb1));
                } else {
                    pk4[p] = 0u;           // k = 90..95 pad
                }
            }
            // fragment slot: [w][ks][rt_w][lg*16+lj] -- lane-contiguous 16B stores
            const int slot = ((w * 3 + ks) * 4 + rt_w) * 64 + lg * 16 + lj;
            uint4 v4; v4.x = pk4[0]; v4.y = pk4[1]; v4.z = pk4[2]; v4.w = pk4[3];
            *(uint4*)&Hs[slot * 8] = v4;
        }
    }

    // ---- per-lane constants for the MFMA/epilogue phase ----
    const float* B2V = wsf + WS_B2V;
    const float* W3V = wsf + WS_W3V;
    float b2j[6], w3j[6];
#pragma unroll
    for (int jt = 0; jt < 6; ++jt) {
        b2j[jt] = B2V[jt * 16 + lj];
        w3j[jt] = W3V[jt * 16 + lj];
    }
    const float B3v = wsf[WS_B3];

    f32x4 acc[4][6];
#pragma unroll
    for (int rt = 0; rt < 4; ++rt)
#pragma unroll
        for (int jt = 0; jt < 6; ++jt)
            acc[rt][jt] = (f32x4){b2j[jt], b2j[jt], b2j[jt], b2j[jt]};

    // NO __syncthreads: wave w reads only fragments it wrote (lgkmcnt handles it)

    // ---- layer 2: fp16 MFMA 16x16x32 ; wave w owns rows w*64 .. w*64+63 ----
    const _Float16* w2f = (const _Float16*)(wsf + WS_W2F);
#pragma unroll
    for (int ks = 0; ks < 3; ++ks) {
        f16x8 bfr[6];
#pragma unroll
        for (int jt = 0; jt < 6; ++jt)
            bfr[jt] = *(const f16x8*)(w2f + (((ks * 6 + jt) * 64 + lane) << 3));
        f16x8 afr[4];
#pragma unroll
        for (int rt = 0; rt < 4; ++rt)
            afr[rt] = *(const f16x8*)&Hs[(((w * 3 + ks) * 4 + rt) * 64 + lane) * 8];
#pragma unroll
        for (int rt = 0; rt < 4; ++rt)
#pragma unroll
            for (int jt = 0; jt < 6; ++jt)
                acc[rt][jt] = __builtin_amdgcn_mfma_f32_16x16x32_f16(
                    afr[rt], bfr[jt], acc[rt][jt], 0, 0, 0);
    }

    // ---- layer 3: elu + W3 on C layout (col=lj, row=4*lg+reg), shfl-reduce ----
    const int lg = lane >> 4;     // C/D row-group (consumer role)
    const int rowbase = blockIdx.x * 256 + w * 64;
#pragma unroll
    for (int rt = 0; rt < 4; ++rt) {
        float p0 = 0.f, p1 = 0.f, p2 = 0.f, p3 = 0.f;
#pragma unroll
        for (int jt = 0; jt < 6; ++jt) {
            p0 += elu_f(acc[rt][jt][0]) * w3j[jt];
            p1 += elu_f(acc[rt][jt][1]) * w3j[jt];
            p2 += elu_f(acc[rt][jt][2]) * w3j[jt];
            p3 += elu_f(acc[rt][jt][3]) * w3j[jt];
        }
#pragma unroll
        for (int mask = 1; mask < 16; mask <<= 1) {
            p0 += __shfl_xor(p0, mask);
            p1 += __shfl_xor(p1, mask);
            p2 += __shfl_xor(p2, mask);
            p3 += __shfl_xor(p3, mask);
        }
        if (lj < 4) {
            const float v = (lj == 0) ? p0 : (lj == 1) ? p1 : (lj == 2) ? p2 : p3;
            out[rowbase + rt * 16 + 4 * lg + lj] = v + B3v;
        }
    }
}

extern "C" void kernel_launch(void* const* d_in, const int* in_sizes, int n_in,
                              void* d_out, int out_size, void* d_ws, size_t ws_size,
                              hipStream_t stream)
{
    const float* x          = (const float*)d_in[0];
    const float* controls   = (const float*)d_in[1];
    const float* W1         = (const float*)d_in[2];
    const float* b1         = (const float*)d_in[3];
    const float* W2         = (const float*)d_in[4];
    const float* b2         = (const float*)d_in[5];
    const float* W3         = (const float*)d_in[6];
    const float* b3         = (const float*)d_in[7];
    const int* inputs_list  = (const int*)d_in[8];
    const int* control_list = (const int*)d_in[9];
    float* out = (float*)d_out;
    float* wsf = (float*)d_ws;

    hipLaunchKernelGGL(prep_kernel, dim3(40), dim3(256), 0, stream,
                       W1, b1, W2, b2, W3, b3, wsf);
    hipLaunchKernelGGL(dnpu_main, dim3(4096), dim3(256), 0, stream,
                       x, controls, inputs_list, control_list, wsf, out);
}

// Round 12
// 159.647 us; speedup vs baseline: 5.9054x; 1.0403x over previous
//
#include <hip/hip_runtime.h>
#include <stdint.h>

// DNPU LRF: 1,048,576 rows of (gather -> 7->90->90->1 MLP).
// Register-diet revision: jt-streaming epilogue (acc[4] + psum[4] instead of
// acc[4][6]) + A-frags held in regs, filled via a 16KB same-wave LDS bounce
// reused across ks (in-order DS, no syncthreads). Target: 4 waves/SIMD.

#define HID 90

typedef float  f32x4 __attribute__((ext_vector_type(4)));
typedef _Float16 f16x8 __attribute__((ext_vector_type(8)));

// Workspace layout (float units unless noted):
//   W1P : [0,720)    90 rows x 8: [k][e], e=0..6 -> W1[e][k], e=7 -> b1[k]
//   B2V : [720,816)  b2 padded to 96 (pad=0)
//   W3V : [816,912)  W3 padded to 96 (pad=0)
//   B3  : [912]      b3 ; [913,928) pad
//   W2F : [928, 928+4608) as fp16: 18 fragments (ks=0..2, jt=0..5) x 64 lanes x 8
//         halves, element (f,l,i) = W2[ks*32+8*(l>>4)+i][jt*16+(l&15)] (0 if OOB)
#define WS_W1P 0
#define WS_B2V 720
#define WS_W3V 816
#define WS_B3  912
#define WS_W2F 928
#define WS_TOT_ELEMS (928 + 9216)   // 928 floats + 9216 halves

__global__ void prep_kernel(const float* __restrict__ W1, const float* __restrict__ b1,
                            const float* __restrict__ W2, const float* __restrict__ b2,
                            const float* __restrict__ W3, const float* __restrict__ b3,
                            float* __restrict__ wsf)
{
    _Float16* w2f = (_Float16*)(wsf + WS_W2F);
    for (int i = blockIdx.x * blockDim.x + threadIdx.x; i < WS_TOT_ELEMS;
         i += gridDim.x * blockDim.x) {
        if (i < 928) {
            float v = 0.f;
            if (i < WS_B2V) {                       // W1P[k][e]
                const int k = i >> 3, e = i & 7;
                v = (e < 7) ? W1[e * HID + k] : b1[k];
            } else if (i < WS_W3V) {
                const int j = i - WS_B2V; v = (j < HID) ? b2[j] : 0.f;
            } else if (i < WS_B3) {
                const int j = i - WS_W3V; v = (j < HID) ? W3[j] : 0.f;
            } else if (i == WS_B3) {
                v = b3[0];
            }                                        // 913..927 -> 0
            wsf[i] = v;
        } else {                                     // W2 fragment-order fp16
            const int e  = i - 928;
            const int f  = e >> 9;                   // fragment 0..17
            const int r  = e & 511;
            const int l  = r >> 3, ii = r & 7;       // lane, elem
            const int ks = f / 6, jt = f - ks * 6;
            const int k  = ks * 32 + ((l >> 4) << 3) + ii;
            const int j  = jt * 16 + (l & 15);
            const float v = (k < HID && j < HID) ? W2[k * HID + j] : 0.f;
            w2f[e] = (_Float16)v;
        }
    }
}

__device__ __forceinline__ float elu_f(float x) {
    return fmaxf(x, 0.f) + (__expf(fminf(x, 0.f)) - 1.f);
}

__device__ __forceinline__ uint32_t pk_f16(float a, float b) {
    auto r = __builtin_amdgcn_cvt_pkrtz(a, b);      // __fp16 ext_vector_type(2)
    return __builtin_bit_cast(uint32_t, r);
}

__global__ __launch_bounds__(256, 4)
void dnpu_main(const float* __restrict__ x,
               const float* __restrict__ controls,
               const int* __restrict__ inputs_list,
               const int* __restrict__ control_list,
               const float* __restrict__ wsf,
               float* __restrict__ out)
{
    // Per-wave A-fragment bounce buffer, REUSED across ks (same-wave DS is
    // in-order; each wave touches only its own [w] slice -> no __syncthreads).
    // [wave][rt][lane][8 halves] = 16 KiB
    __shared__ alignas(16) _Float16 Hs[4 * 4 * 64 * 8];

    const int t    = threadIdx.x;
    const int row  = blockIdx.x * 256 + t;
    const int b    = row >> 10;
    const int n    = row & 1023;
    const int ph   = n >> 5, pw = n & 31;
    const int w    = t >> 6;
    const int lane = t & 63;
    const int rt_w = lane >> 4;   // producer row-tile
    const int lj   = lane & 15;   // A-row / C-col within tile

    // ---- gather 2x2 patch + electrode assembly (branchless inverse scatter) ----
    const float* xp = x + ((size_t)b << 12) + (ph * 2) * 64 + pw * 2;
    const float2 pA = *(const float2*)xp;
    const float2 pB = *(const float2*)(xp + 64);

    const int4 il  = *(const int4*)(inputs_list + (n << 2));
    const int  cl0 = control_list[n * 3 + 0];
    const int  cl1 = control_list[n * 3 + 1];
    const int  cl2 = control_list[n * 3 + 2];
    const float c0 = controls[n * 3 + 0];
    const float c1 = controls[n * 3 + 1];
    const float c2 = controls[n * 3 + 2];

    float E[8];
    E[7] = 1.0f;                          // pairs with b1 folded into W1P[k][7]
#pragma unroll
    for (int e = 0; e < 7; ++e) {
        float v = 0.f;
        v = (il.x == e) ? pA.x : v;
        v = (il.y == e) ? pA.y : v;
        v = (il.z == e) ? pB.x : v;
        v = (il.w == e) ? pB.y : v;
        v = (cl0 == e) ? c0 : v;
        v = (cl1 == e) ? c1 : v;
        v = (cl2 == e) ? c2 : v;
        E[e] = v;
    }

    // ---- layer 1: fp32 -> packed fp16; LDS bounce per ks fills af[3][4] ----
    const float* W1P = wsf + WS_W1P;
    uint4 af[3][4];                       // 48 VGPRs, static indices only
#pragma unroll
    for (int ks = 0; ks < 3; ++ks) {
#pragma unroll
        for (int lg = 0; lg < 4; ++lg) {
            uint32_t pk4[4];
#pragma unroll
            for (int p = 0; p < 4; ++p) {
                const int k = ks * 32 + lg * 8 + p * 2;
                if (k < HID) {
                    const float* wA = W1P + (k << 3);
                    float pa0 = 0.f, pa1 = 0.f, pb0 = 0.f, pb1 = 0.f;
#pragma unroll
                    for (int e = 0; e < 8; e += 2) {
                        pa0 = __builtin_fmaf(E[e],     wA[e],     pa0);
                        pa1 = __builtin_fmaf(E[e + 1], wA[e + 1], pa1);
                        pb0 = __builtin_fmaf(E[e],     wA[e + 8], pb0);
                        pb1 = __builtin_fmaf(E[e + 1], wA[e + 9], pb1);
                    }
                    pk4[p] = pk_f16(elu_f(pa0 + pa1), elu_f(pb0 + pb1));
                } else {
                    pk4[p] = 0u;           // k = 90..95 pad
                }
            }
            const int slot = (w * 4 + rt_w) * 64 + lg * 16 + lj;  // lane-contig 16B
            uint4 v4; v4.x = pk4[0]; v4.y = pk4[1]; v4.z = pk4[2]; v4.w = pk4[3];
            *(uint4*)&Hs[slot * 8] = v4;
        }
        // read back this ks-slice as A-fragments (same wave; DS in-order)
#pragma unroll
        for (int rt = 0; rt < 4; ++rt)
            af[ks][rt] = *(const uint4*)&Hs[((w * 4 + rt) * 64 + lane) * 8];
    }

    // ---- per-lane epilogue constants ----
    const float* B2V = wsf + WS_B2V;
    const float* W3V = wsf + WS_W3V;
    float b2j[6], w3j[6];
#pragma unroll
    for (int jt = 0; jt < 6; ++jt) {
        b2j[jt] = B2V[jt * 16 + lj];
        w3j[jt] = W3V[jt * 16 + lj];
    }
    const float B3v = wsf[WS_B3];

    // ---- layer 2+3, jt-streamed: acc[4] live per jt, psum accumulates ----
    const _Float16* w2f = (const _Float16*)(wsf + WS_W2F);
    f32x4 psum[4];
#pragma unroll
    for (int rt = 0; rt < 4; ++rt) psum[rt] = (f32x4){0.f, 0.f, 0.f, 0.f};

#pragma unroll
    for (int jt = 0; jt < 6; ++jt) {
        f32x4 acc[4];
#pragma unroll
        for (int rt = 0; rt < 4; ++rt)
            acc[rt] = (f32x4){b2j[jt], b2j[jt], b2j[jt], b2j[jt]};
#pragma unroll
        for (int ks = 0; ks < 3; ++ks) {
            const f16x8 bfr = *(const f16x8*)(w2f + (((ks * 6 + jt) * 64 + lane) << 3));
#pragma unroll
            for (int rt = 0; rt < 4; ++rt)
                acc[rt] = __builtin_amdgcn_mfma_f32_16x16x32_f16(
                    __builtin_bit_cast(f16x8, af[ks][rt]), bfr, acc[rt], 0, 0, 0);
        }
        const float w3 = w3j[jt];
#pragma unroll
        for (int rt = 0; rt < 4; ++rt) {
            psum[rt][0] = __builtin_fmaf(elu_f(acc[rt][0]), w3, psum[rt][0]);
            psum[rt][1] = __builtin_fmaf(elu_f(acc[rt][1]), w3, psum[rt][1]);
            psum[rt][2] = __builtin_fmaf(elu_f(acc[rt][2]), w3, psum[rt][2]);
            psum[rt][3] = __builtin_fmaf(elu_f(acc[rt][3]), w3, psum[rt][3]);
        }
    }

    // ---- 16-lane shfl reduce + store (C layout: col=lj, row=4*lg+reg) ----
    const int lg = lane >> 4;
    const int rowbase = blockIdx.x * 256 + w * 64;
#pragma unroll
    for (int rt = 0; rt < 4; ++rt) {
        float p0 = psum[rt][0], p1 = psum[rt][1], p2 = psum[rt][2], p3 = psum[rt][3];
#pragma unroll
        for (int mask = 1; mask < 16; mask <<= 1) {
            p0 += __shfl_xor(p0, mask);
            p1 += __shfl_xor(p1, mask);
            p2 += __shfl_xor(p2, mask);
            p3 += __shfl_xor(p3, mask);
        }
        if (lj < 4) {
            const float v = (lj == 0) ? p0 : (lj == 1) ? p1 : (lj == 2) ? p2 : p3;
            out[rowbase + rt * 16 + 4 * lg + lj] = v + B3v;
        }
    }
}

extern "C" void kernel_launch(void* const* d_in, const int* in_sizes, int n_in,
                              void* d_out, int out_size, void* d_ws, size_t ws_size,
                              hipStream_t stream)
{
    const float* x          = (const float*)d_in[0];
    const float* controls   = (const float*)d_in[1];
    const float* W1         = (const float*)d_in[2];
    const float* b1         = (const float*)d_in[3];
    const float* W2         = (const float*)d_in[4];
    const float* b2         = (const float*)d_in[5];
    const float* W3         = (const float*)d_in[6];
    const float* b3         = (const float*)d_in[7];
    const int* inputs_list  = (const int*)d_in[8];
    const int* control_list = (const int*)d_in[9];
    float* out = (float*)d_out;
    float* wsf = (float*)d_ws;

    hipLaunchKernelGGL(prep_kernel, dim3(40), dim3(256), 0, stream,
                       W1, b1, W2, b2, W3, b3, wsf);
    hipLaunchKernelGGL(dnpu_main, dim3(4096), dim3(256), 0, stream,
                       x, controls, inputs_list, control_list, wsf, out);
}

// Round 13
// 153.470 us; speedup vs baseline: 6.1431x; 1.0402x over previous
//
#include <hip/hip_runtime.h>
#include <stdint.h>

// DNPU LRF: 1,048,576 rows of (gather -> 7->90->90->1 MLP).
// jt-streaming epilogue (acc[4]+psum[4]) with A-fragments LDS-RESIDENT
// (48KB, written once in frag order, re-read per jt) -- kills the 63MB
// scratch spill of the reg-resident af[] variant. No __syncthreads (same-wave DS).

#define HID 90

typedef float  f32x4 __attribute__((ext_vector_type(4)));
typedef _Float16 f16x8 __attribute__((ext_vector_type(8)));

// Workspace layout (float units unless noted):
//   W1P : [0,720)    90 rows x 8: [k][e], e=0..6 -> W1[e][k], e=7 -> b1[k]
//   B2V : [720,816)  b2 padded to 96 (pad=0)
//   W3V : [816,912)  W3 padded to 96 (pad=0)
//   B3  : [912]      b3 ; [913,928) pad
//   W2F : [928, 928+4608) as fp16: 18 fragments (ks=0..2, jt=0..5) x 64 lanes x 8
//         halves, element (f,l,i) = W2[ks*32+8*(l>>4)+i][jt*16+(l&15)] (0 if OOB)
#define WS_W1P 0
#define WS_B2V 720
#define WS_W3V 816
#define WS_B3  912
#define WS_W2F 928
#define WS_TOT_ELEMS (928 + 9216)   // 928 floats + 9216 halves

__global__ void prep_kernel(const float* __restrict__ W1, const float* __restrict__ b1,
                            const float* __restrict__ W2, const float* __restrict__ b2,
                            const float* __restrict__ W3, const float* __restrict__ b3,
                            float* __restrict__ wsf)
{
    _Float16* w2f = (_Float16*)(wsf + WS_W2F);
    for (int i = blockIdx.x * blockDim.x + threadIdx.x; i < WS_TOT_ELEMS;
         i += gridDim.x * blockDim.x) {
        if (i < 928) {
            float v = 0.f;
            if (i < WS_B2V) {                       // W1P[k][e]
                const int k = i >> 3, e = i & 7;
                v = (e < 7) ? W1[e * HID + k] : b1[k];
            } else if (i < WS_W3V) {
                const int j = i - WS_B2V; v = (j < HID) ? b2[j] : 0.f;
            } else if (i < WS_B3) {
                const int j = i - WS_W3V; v = (j < HID) ? W3[j] : 0.f;
            } else if (i == WS_B3) {
                v = b3[0];
            }                                        // 913..927 -> 0
            wsf[i] = v;
        } else {                                     // W2 fragment-order fp16
            const int e  = i - 928;
            const int f  = e >> 9;                   // fragment 0..17
            const int r  = e & 511;
            const int l  = r >> 3, ii = r & 7;       // lane, elem
            const int ks = f / 6, jt = f - ks * 6;
            const int k  = ks * 32 + ((l >> 4) << 3) + ii;
            const int j  = jt * 16 + (l & 15);
            const float v = (k < HID && j < HID) ? W2[k * HID + j] : 0.f;
            w2f[e] = (_Float16)v;
        }
    }
}

__device__ __forceinline__ float elu_f(float x) {
    return fmaxf(x, 0.f) + (__expf(fminf(x, 0.f)) - 1.f);
}

__device__ __forceinline__ uint32_t pk_f16(float a, float b) {
    auto r = __builtin_amdgcn_cvt_pkrtz(a, b);      // __fp16 ext_vector_type(2)
    return __builtin_bit_cast(uint32_t, r);
}

__global__ __launch_bounds__(256, 3)
void dnpu_main(const float* __restrict__ x,
               const float* __restrict__ controls,
               const int* __restrict__ inputs_list,
               const int* __restrict__ control_list,
               const float* __restrict__ wsf,
               float* __restrict__ out)
{
    // h1 in A-fragment order: [wave][ks][rt][lane][8 halves] = 48 KiB.
    // Written once by layer 1, re-read per jt by the MFMA loop (same wave only).
    __shared__ alignas(16) _Float16 Hs[4 * 3 * 4 * 64 * 8];

    const int t    = threadIdx.x;
    const int row  = blockIdx.x * 256 + t;
    const int b    = row >> 10;
    const int n    = row & 1023;
    const int ph   = n >> 5, pw = n & 31;
    const int w    = t >> 6;
    const int lane = t & 63;
    const int rt_w = lane >> 4;   // producer row-tile
    const int lj   = lane & 15;   // A-row / C-col within tile

    // ---- gather 2x2 patch + electrode assembly (branchless inverse scatter) ----
    const float* xp = x + ((size_t)b << 12) + (ph * 2) * 64 + pw * 2;
    const float2 pA = *(const float2*)xp;
    const float2 pB = *(const float2*)(xp + 64);

    const int4 il  = *(const int4*)(inputs_list + (n << 2));
    const int  cl0 = control_list[n * 3 + 0];
    const int  cl1 = control_list[n * 3 + 1];
    const int  cl2 = control_list[n * 3 + 2];
    const float c0 = controls[n * 3 + 0];
    const float c1 = controls[n * 3 + 1];
    const float c2 = controls[n * 3 + 2];

    float E[8];
    E[7] = 1.0f;                          // pairs with b1 folded into W1P[k][7]
#pragma unroll
    for (int e = 0; e < 7; ++e) {
        float v = 0.f;
        v = (il.x == e) ? pA.x : v;
        v = (il.y == e) ? pA.y : v;
        v = (il.z == e) ? pB.x : v;
        v = (il.w == e) ? pB.y : v;
        v = (cl0 == e) ? c0 : v;
        v = (cl1 == e) ? c1 : v;
        v = (cl2 == e) ? c2 : v;
        E[e] = v;
    }

    // ---- layer 1: fp32 -> packed fp16 -> LDS in A-fragment order ----
    const float* W1P = wsf + WS_W1P;
#pragma unroll
    for (int ks = 0; ks < 3; ++ks) {
#pragma unroll
        for (int lg = 0; lg < 4; ++lg) {
            uint32_t pk4[4];
#pragma unroll
            for (int p = 0; p < 4; ++p) {
                const int k = ks * 32 + lg * 8 + p * 2;
                if (k < HID) {
                    const float* wA = W1P + (k << 3);
                    float pa0 = 0.f, pa1 = 0.f, pb0 = 0.f, pb1 = 0.f;
#pragma unroll
                    for (int e = 0; e < 8; e += 2) {
                        pa0 = __builtin_fmaf(E[e],     wA[e],     pa0);
                        pa1 = __builtin_fmaf(E[e + 1], wA[e + 1], pa1);
                        pb0 = __builtin_fmaf(E[e],     wA[e + 8], pb0);
                        pb1 = __builtin_fmaf(E[e + 1], wA[e + 9], pb1);
                    }
                    pk4[p] = pk_f16(elu_f(pa0 + pa1), elu_f(pb0 + pb1));
                } else {
                    pk4[p] = 0u;           // k = 90..95 pad
                }
            }
            const int slot = ((w * 3 + ks) * 4 + rt_w) * 64 + lg * 16 + lj;
            uint4 v4; v4.x = pk4[0]; v4.y = pk4[1]; v4.z = pk4[2]; v4.w = pk4[3];
            *(uint4*)&Hs[slot * 8] = v4;   // lane-contiguous 16B, conflict-free
        }
    }

    // ---- per-lane epilogue constants ----
    const float* B2V = wsf + WS_B2V;
    const float* W3V = wsf + WS_W3V;
    float b2j[6], w3j[6];
#pragma unroll
    for (int jt = 0; jt < 6; ++jt) {
        b2j[jt] = B2V[jt * 16 + lj];
        w3j[jt] = W3V[jt * 16 + lj];
    }
    const float B3v = wsf[WS_B3];

    // ---- layer 2+3, jt-streamed; A-frags re-read from LDS (no reg residency) ----
    const _Float16* w2f = (const _Float16*)(wsf + WS_W2F);
    f32x4 psum[4];
#pragma unroll
    for (int rt = 0; rt < 4; ++rt) psum[rt] = (f32x4){0.f, 0.f, 0.f, 0.f};

#pragma unroll
    for (int jt = 0; jt < 6; ++jt) {
        f32x4 acc[4];
#pragma unroll
        for (int rt = 0; rt < 4; ++rt)
            acc[rt] = (f32x4){b2j[jt], b2j[jt], b2j[jt], b2j[jt]};
#pragma unroll
        for (int ks = 0; ks < 3; ++ks) {
            const f16x8 bfr = *(const f16x8*)(w2f + (((ks * 6 + jt) * 64 + lane) << 3));
#pragma unroll
            for (int rt = 0; rt < 4; ++rt) {
                const f16x8 afr = *(const f16x8*)&Hs[(((w * 3 + ks) * 4 + rt) * 64 + lane) * 8];
                acc[rt] = __builtin_amdgcn_mfma_f32_16x16x32_f16(afr, bfr, acc[rt], 0, 0, 0);
            }
        }
        const float w3 = w3j[jt];
#pragma unroll
        for (int rt = 0; rt < 4; ++rt) {
            psum[rt][0] = __builtin_fmaf(elu_f(acc[rt][0]), w3, psum[rt][0]);
            psum[rt][1] = __builtin_fmaf(elu_f(acc[rt][1]), w3, psum[rt][1]);
            psum[rt][2] = __builtin_fmaf(elu_f(acc[rt][2]), w3, psum[rt][2]);
            psum[rt][3] = __builtin_fmaf(elu_f(acc[rt][3]), w3, psum[rt][3]);
        }
    }

    // ---- 16-lane shfl reduce + store (C layout: col=lj, row=4*lg+reg) ----
    const int lg = lane >> 4;
    const int rowbase = blockIdx.x * 256 + w * 64;
#pragma unroll
    for (int rt = 0; rt < 4; ++rt) {
        float p0 = psum[rt][0], p1 = psum[rt][1], p2 = psum[rt][2], p3 = psum[rt][3];
#pragma unroll
        for (int mask = 1; mask < 16; mask <<= 1) {
            p0 += __shfl_xor(p0, mask);
            p1 += __shfl_xor(p1, mask);
            p2 += __shfl_xor(p2, mask);
            p3 += __shfl_xor(p3, mask);
        }
        if (lj < 4) {
            const float v = (lj == 0) ? p0 : (lj == 1) ? p1 : (lj == 2) ? p2 : p3;
            out[rowbase + rt * 16 + 4 * lg + lj] = v + B3v;
        }
    }
}

extern "C" void kernel_launch(void* const* d_in, const int* in_sizes, int n_in,
                              void* d_out, int out_size, void* d_ws, size_t ws_size,
                              hipStream_t stream)
{
    const float* x          = (const float*)d_in[0];
    const float* controls   = (const float*)d_in[1];
    const float* W1         = (const float*)d_in[2];
    const float* b1         = (const float*)d_in[3];
    const float* W2         = (const float*)d_in[4];
    const float* b2         = (const float*)d_in[5];
    const float* W3         = (const float*)d_in[6];
    const float* b3         = (const float*)d_in[7];
    const int* inputs_list  = (const int*)d_in[8];
    const int* control_list = (const int*)d_in[9];
    float* out = (float*)d_out;
    float* wsf = (float*)d_ws;

    hipLaunchKernelGGL(prep_kernel, dim3(40), dim3(256), 0, stream,
                       W1, b1, W2, b2, W3, b3, wsf);
    hipLaunchKernelGGL(dnpu_main, dim3(4096), dim3(256), 0, stream,
                       x, controls, inputs_list, control_list, wsf, out);
}

// Round 14
// 147.592 us; speedup vs baseline: 6.3877x; 1.0398x over previous
//
#include <hip/hip_runtime.h>
#include <stdint.h>

// DNPU LRF: 1,048,576 rows of (gather -> 7->90->90->1 MLP).
// r14: layer-1 dot products via v_dot2_f32_f16 (fp16 E/W1 pairs, f32 accum,
// b1 fp32) -- halves the dominant VALU FMA block. Layer 2/3 unchanged:
// h1 fp16 -> LDS A-fragments (48KB), jt-streamed fp16 MFMA, shfl-reduce.

#define HID 90

typedef float  f32x4 __attribute__((ext_vector_type(4)));
typedef _Float16 f16x8 __attribute__((ext_vector_type(8)));
typedef _Float16 h2    __attribute__((ext_vector_type(2)));

// Workspace layout (float-slot units unless noted):
//   W1D : [0,360)    90 k x 4 dwords, dword ep = pack_f16(W1[2ep][k], W1[2ep+1][k])
//                    (ep=3: hi half = 0; b1 lives in B1V as f32)
//   B1V : [360,456)  b1 padded to 96 (pad=0)
//   B2V : [456,552)  b2 padded to 96 (pad=0)
//   W3V : [552,648)  W3 padded to 96 (pad=0)
//   B3  : [648]      b3 ; [649,656) pad
//   W2F : [656, 656+4608) as fp16: 18 fragments (ks=0..2, jt=0..5) x 64 lanes x 8
//         halves, element (f,l,i) = W2[ks*32+8*(l>>4)+i][jt*16+(l&15)] (0 if OOB)
#define WS_W1D 0
#define WS_B1V 360
#define WS_B2V 456
#define WS_W3V 552
#define WS_B3  648
#define WS_W2F 656
#define WS_TOT_ITEMS (656 + 9216)   // 656 float slots + 9216 halves

__device__ __forceinline__ uint32_t pk_f16(float a, float b) {
    auto r = __builtin_amdgcn_cvt_pkrtz(a, b);      // __fp16 ext_vector_type(2)
    return __builtin_bit_cast(uint32_t, r);
}

__global__ void prep_kernel(const float* __restrict__ W1, const float* __restrict__ b1,
                            const float* __restrict__ W2, const float* __restrict__ b2,
                            const float* __restrict__ W3, const float* __restrict__ b3,
                            float* __restrict__ wsf)
{
    _Float16* w2f = (_Float16*)(wsf + WS_W2F);
    for (int i = blockIdx.x * blockDim.x + threadIdx.x; i < WS_TOT_ITEMS;
         i += gridDim.x * blockDim.x) {
        if (i < 656) {
            if (i < WS_B1V) {                        // W1D[k][ep] fp16 pair
                const int k = i >> 2, ep = i & 3;
                const float lo = W1[(2 * ep) * HID + k];
                const float hi = (ep < 3) ? W1[(2 * ep + 1) * HID + k] : 0.f;
                const uint32_t u = pk_f16(lo, hi);
                wsf[i] = __builtin_bit_cast(float, u);
            } else {
                float v = 0.f;
                if (i < WS_B2V)      { const int j = i - WS_B1V; v = (j < HID) ? b1[j] : 0.f; }
                else if (i < WS_W3V) { const int j = i - WS_B2V; v = (j < HID) ? b2[j] : 0.f; }
                else if (i < WS_B3)  { const int j = i - WS_W3V; v = (j < HID) ? W3[j] : 0.f; }
                else if (i == WS_B3) { v = b3[0]; }   // 649..655 -> 0
                wsf[i] = v;
            }
        } else {                                     // W2 fragment-order fp16
            const int e  = i - 656;
            const int f  = e >> 9;                   // fragment 0..17
            const int r  = e & 511;
            const int l  = r >> 3, ii = r & 7;       // lane, elem
            const int ks = f / 6, jt = f - ks * 6;
            const int k  = ks * 32 + ((l >> 4) << 3) + ii;
            const int j  = jt * 16 + (l & 15);
            const float v = (k < HID && j < HID) ? W2[k * HID + j] : 0.f;
            w2f[e] = (_Float16)v;
        }
    }
}

__device__ __forceinline__ float elu_f(float x) {
    return fmaxf(x, 0.f) + (__expf(fminf(x, 0.f)) - 1.f);
}

__device__ __forceinline__ float fdot2f(uint32_t a, uint32_t b, float c) {
    return __builtin_amdgcn_fdot2(__builtin_bit_cast(h2, a),
                                  __builtin_bit_cast(h2, b), c, false);
}

__global__ __launch_bounds__(256, 3)
void dnpu_main(const float* __restrict__ x,
               const float* __restrict__ controls,
               const int* __restrict__ inputs_list,
               const int* __restrict__ control_list,
               const float* __restrict__ wsf,
               float* __restrict__ out)
{
    // h1 in A-fragment order: [wave][ks][rt][lane][8 halves] = 48 KiB.
    __shared__ alignas(16) _Float16 Hs[4 * 3 * 4 * 64 * 8];

    const int t    = threadIdx.x;
    const int row  = blockIdx.x * 256 + t;
    const int b    = row >> 10;
    const int n    = row & 1023;
    const int ph   = n >> 5, pw = n & 31;
    const int w    = t >> 6;
    const int lane = t & 63;
    const int rt_w = lane >> 4;   // producer row-tile
    const int lj   = lane & 15;   // A-row / C-col within tile

    // ---- gather 2x2 patch + electrode assembly (branchless inverse scatter) ----
    const float* xp = x + ((size_t)b << 12) + (ph * 2) * 64 + pw * 2;
    const float2 pA = *(const float2*)xp;
    const float2 pB = *(const float2*)(xp + 64);

    const int4 il  = *(const int4*)(inputs_list + (n << 2));
    const int  cl0 = control_list[n * 3 + 0];
    const int  cl1 = control_list[n * 3 + 1];
    const int  cl2 = control_list[n * 3 + 2];
    const float c0 = controls[n * 3 + 0];
    const float c1 = controls[n * 3 + 1];
    const float c2 = controls[n * 3 + 2];

    float E[7];
#pragma unroll
    for (int e = 0; e < 7; ++e) {
        float v = 0.f;
        v = (il.x == e) ? pA.x : v;
        v = (il.y == e) ? pA.y : v;
        v = (il.z == e) ? pB.x : v;
        v = (il.w == e) ? pB.y : v;
        v = (cl0 == e) ? c0 : v;
        v = (cl1 == e) ? c1 : v;
        v = (cl2 == e) ? c2 : v;
        E[e] = v;
    }
    // packed fp16 electrode pairs for fdot2 (pair 3 hi pairs with W1D's zero)
    const uint32_t ep0 = pk_f16(E[0], E[1]);
    const uint32_t ep1 = pk_f16(E[2], E[3]);
    const uint32_t ep2 = pk_f16(E[4], E[5]);
    const uint32_t ep3 = pk_f16(E[6], 0.f);

    // ---- layer 1: fdot2 pairs -> fp16 -> LDS in A-fragment order ----
    const uint32_t* w1d = (const uint32_t*)(wsf + WS_W1D);
    const float*    B1V = wsf + WS_B1V;
#pragma unroll
    for (int ks = 0; ks < 3; ++ks) {
#pragma unroll
        for (int lg = 0; lg < 4; ++lg) {
            uint32_t pk4[4];
#pragma unroll
            for (int p = 0; p < 4; ++p) {
                const int k = ks * 32 + lg * 8 + p * 2;
                if (k < HID) {
                    const uint4 wa = *(const uint4*)(w1d + (k << 2));       // row k
                    const uint4 wb = *(const uint4*)(w1d + (k << 2) + 4);   // row k+1
                    float accA = B1V[k];
                    float accB = B1V[k + 1];
                    accA = fdot2f(ep0, wa.x, accA);
                    accA = fdot2f(ep1, wa.y, accA);
                    accA = fdot2f(ep2, wa.z, accA);
                    accA = fdot2f(ep3, wa.w, accA);
                    accB = fdot2f(ep0, wb.x, accB);
                    accB = fdot2f(ep1, wb.y, accB);
                    accB = fdot2f(ep2, wb.z, accB);
                    accB = fdot2f(ep3, wb.w, accB);
                    pk4[p] = pk_f16(elu_f(accA), elu_f(accB));
                } else {
                    pk4[p] = 0u;           // k = 90..95 pad
                }
            }
            const int slot = ((w * 3 + ks) * 4 + rt_w) * 64 + lg * 16 + lj;
            uint4 v4; v4.x = pk4[0]; v4.y = pk4[1]; v4.z = pk4[2]; v4.w = pk4[3];
            *(uint4*)&Hs[slot * 8] = v4;   // lane-contiguous 16B, conflict-free
        }
    }

    // ---- per-lane epilogue constants ----
    const float* B2V = wsf + WS_B2V;
    const float* W3V = wsf + WS_W3V;
    float b2j[6], w3j[6];
#pragma unroll
    for (int jt = 0; jt < 6; ++jt) {
        b2j[jt] = B2V[jt * 16 + lj];
        w3j[jt] = W3V[jt * 16 + lj];
    }
    const float B3v = wsf[WS_B3];

    // ---- layer 2+3, jt-streamed; A-frags re-read from LDS ----
    const _Float16* w2f = (const _Float16*)(wsf + WS_W2F);
    f32x4 psum[4];
#pragma unroll
    for (int rt = 0; rt < 4; ++rt) psum[rt] = (f32x4){0.f, 0.f, 0.f, 0.f};

#pragma unroll
    for (int jt = 0; jt < 6; ++jt) {
        f32x4 acc[4];
#pragma unroll
        for (int rt = 0; rt < 4; ++rt)
            acc[rt] = (f32x4){b2j[jt], b2j[jt], b2j[jt], b2j[jt]};
#pragma unroll
        for (int ks = 0; ks < 3; ++ks) {
            const f16x8 bfr = *(const f16x8*)(w2f + (((ks * 6 + jt) * 64 + lane) << 3));
#pragma unroll
            for (int rt = 0; rt < 4; ++rt) {
                const f16x8 afr = *(const f16x8*)&Hs[(((w * 3 + ks) * 4 + rt) * 64 + lane) * 8];
                acc[rt] = __builtin_amdgcn_mfma_f32_16x16x32_f16(afr, bfr, acc[rt], 0, 0, 0);
            }
        }
        const float w3 = w3j[jt];
#pragma unroll
        for (int rt = 0; rt < 4; ++rt) {
            psum[rt][0] = __builtin_fmaf(elu_f(acc[rt][0]), w3, psum[rt][0]);
            psum[rt][1] = __builtin_fmaf(elu_f(acc[rt][1]), w3, psum[rt][1]);
            psum[rt][2] = __builtin_fmaf(elu_f(acc[rt][2]), w3, psum[rt][2]);
            psum[rt][3] = __builtin_fmaf(elu_f(acc[rt][3]), w3, psum[rt][3]);
        }
    }

    // ---- 16-lane shfl reduce + store (C layout: col=lj, row=4*lg+reg) ----
    const int lg = lane >> 4;
    const int rowbase = blockIdx.x * 256 + w * 64;
#pragma unroll
    for (int rt = 0; rt < 4; ++rt) {
        float p0 = psum[rt][0], p1 = psum[rt][1], p2 = psum[rt][2], p3 = psum[rt][3];
#pragma unroll
        for (int mask = 1; mask < 16; mask <<= 1) {
            p0 += __shfl_xor(p0, mask);
            p1 += __shfl_xor(p1, mask);
            p2 += __shfl_xor(p2, mask);
            p3 += __shfl_xor(p3, mask);
        }
        if (lj < 4) {
            const float v = (lj == 0) ? p0 : (lj == 1) ? p1 : (lj == 2) ? p2 : p3;
            out[rowbase + rt * 16 + 4 * lg + lj] = v + B3v;
        }
    }
}

extern "C" void kernel_launch(void* const* d_in, const int* in_sizes, int n_in,
                              void* d_out, int out_size, void* d_ws, size_t ws_size,
                              hipStream_t stream)
{
    const float* x          = (const float*)d_in[0];
    const float* controls   = (const float*)d_in[1];
    const float* W1         = (const float*)d_in[2];
    const float* b1         = (const float*)d_in[3];
    const float* W2         = (const float*)d_in[4];
    const float* b2         = (const float*)d_in[5];
    const float* W3         = (const float*)d_in[6];
    const float* b3         = (const float*)d_in[7];
    const int* inputs_list  = (const int*)d_in[8];
    const int* control_list = (const int*)d_in[9];
    float* out = (float*)d_out;
    float* wsf = (float*)d_ws;

    hipLaunchKernelGGL(prep_kernel, dim3(40), dim3(256), 0, stream,
                       W1, b1, W2, b2, W3, b3, wsf);
    hipLaunchKernelGGL(dnpu_main, dim3(4096), dim3(256), 0, stream,
                       x, controls, inputs_list, control_list, wsf, out);
}

// Round 15
// 137.638 us; speedup vs baseline: 6.8497x; 1.0723x over previous
//
#include <hip/hip_runtime.h>
#include <stdint.h>

// DNPU LRF: 1,048,576 rows of (gather -> 7->90->90->1 MLP).
// r15: BOTH layers on MFMA. Layer 1 = mfma(A=W1^T frags [16m x 32k, k=electrode,
// b1 at k=7], B=E^T frags via shfl) -> 24 MFMAs replace the 360-fdot2 block.
// ELU+pack of C goes straight to the Hs A-fragment slots (derived routing).
// Layer 2/3 unchanged: jt-streamed fp16 MFMA + shfl-reduce.

#define HID 90

typedef float  f32x4 __attribute__((ext_vector_type(4)));
typedef _Float16 f16x8 __attribute__((ext_vector_type(8)));

// Workspace layout (float-slot units unless noted):
//   W1A : [0,1536)    6 layer-1 A-frags x 64 lanes x 4 dwords (8 fp16 halves).
//         frag mt, lane l, elem i -> A[m=l&15][e=8*(l>>4)+i] of tile m=mt*16+..:
//         e<7 -> W1[e][m], e==7 -> b1[m], (l>>4)>0 or m>=90 -> 0
//   B2V : [1536,1632)  b2 padded to 96 (pad=0)
//   W3V : [1632,1728)  W3 padded to 96 (pad=0)
//   B3  : [1728]       b3 ; [1729,1744) pad
//   W2F : [1744, 1744+4608) as fp16: 18 layer-2 B-frags (ks=0..2, jt=0..5) x 64
//         lanes x 8 halves, elem (f,l,i) = W2[ks*32+8*(l>>4)+i][jt*16+(l&15)]
#define WS_W1A 0
#define WS_B2V 1536
#define WS_W3V 1632
#define WS_B3  1728
#define WS_W2F 1744
#define WS_TOT_ITEMS (1744 + 9216)   // float slots then half-indices

__device__ __forceinline__ uint32_t pk_f16(float a, float b) {
    auto r = __builtin_amdgcn_cvt_pkrtz(a, b);      // __fp16 ext_vector_type(2)
    return __builtin_bit_cast(uint32_t, r);
}

__global__ void prep_kernel(const float* __restrict__ W1, const float* __restrict__ b1,
                            const float* __restrict__ W2, const float* __restrict__ b2,
                            const float* __restrict__ W3, const float* __restrict__ b3,
                            float* __restrict__ wsf)
{
    _Float16* w2f = (_Float16*)(wsf + WS_W2F);
    for (int i = blockIdx.x * blockDim.x + threadIdx.x; i < WS_TOT_ITEMS;
         i += gridDim.x * blockDim.x) {
        if (i < WS_B2V) {                            // W1A dword
            const int mt = i >> 8;                   // 256 dwords per frag
            const int l  = (i >> 2) & 63;
            const int dp = i & 3;
            const int hi = l >> 4, lj = l & 15;
            const int m  = mt * 16 + lj;
            float v0 = 0.f, v1 = 0.f;
            if (hi == 0 && m < HID) {
                const int e0 = 2 * dp, e1 = 2 * dp + 1;
                v0 = (e0 < 7) ? W1[e0 * HID + m] : b1[m];
                v1 = (e1 < 7) ? W1[e1 * HID + m] : b1[m];
            }
            wsf[i] = __builtin_bit_cast(float, pk_f16(v0, v1));
        } else if (i < WS_W2F) {
            float v = 0.f;
            if (i < WS_W3V)      { const int j = i - WS_B2V; v = (j < HID) ? b2[j] : 0.f; }
            else if (i < WS_B3)  { const int j = i - WS_W3V; v = (j < HID) ? W3[j] : 0.f; }
            else if (i == WS_B3) { v = b3[0]; }       // 1729..1743 -> 0
            wsf[i] = v;
        } else {                                     // W2 fragment-order fp16
            const int e  = i - WS_W2F;
            const int f  = e >> 9;                   // fragment 0..17
            const int r  = e & 511;
            const int l  = r >> 3, ii = r & 7;       // lane, elem
            const int ks = f / 6, jt = f - ks * 6;
            const int k  = ks * 32 + ((l >> 4) << 3) + ii;
            const int j  = jt * 16 + (l & 15);
            const float v = (k < HID && j < HID) ? W2[k * HID + j] : 0.f;
            w2f[e] = (_Float16)v;
        }
    }
}

__device__ __forceinline__ float elu_f(float x) {
    return fmaxf(x, 0.f) + (__expf(fminf(x, 0.f)) - 1.f);
}

__global__ __launch_bounds__(256, 3)
void dnpu_main(const float* __restrict__ x,
               const float* __restrict__ controls,
               const int* __restrict__ inputs_list,
               const int* __restrict__ control_list,
               const float* __restrict__ wsf,
               float* __restrict__ out)
{
    // h1 in layer-2 A-fragment order: [wave][ks][rt][lane][8 halves] = 48 KiB.
    __shared__ alignas(16) _Float16 Hs[4 * 3 * 4 * 64 * 8];

    const int t    = threadIdx.x;
    const int row  = blockIdx.x * 256 + t;
    const int b    = row >> 10;
    const int n    = row & 1023;
    const int ph   = n >> 5, pw = n & 31;
    const int w    = t >> 6;
    const int lane = t & 63;
    const int hi   = lane >> 4;
    const int lj   = lane & 15;
    const bool hi0 = (hi == 0);

    // ---- gather 2x2 patch + electrode assembly (branchless inverse scatter) ----
    const float* xp = x + ((size_t)b << 12) + (ph * 2) * 64 + pw * 2;
    const float2 pA = *(const float2*)xp;
    const float2 pB = *(const float2*)(xp + 64);

    const int4 il  = *(const int4*)(inputs_list + (n << 2));
    const int  cl0 = control_list[n * 3 + 0];
    const int  cl1 = control_list[n * 3 + 1];
    const int  cl2 = control_list[n * 3 + 2];
    const float c0 = controls[n * 3 + 0];
    const float c1 = controls[n * 3 + 1];
    const float c2 = controls[n * 3 + 2];

    float E[7];
#pragma unroll
    for (int e = 0; e < 7; ++e) {
        float v = 0.f;
        v = (il.x == e) ? pA.x : v;
        v = (il.y == e) ? pA.y : v;
        v = (il.z == e) ? pB.x : v;
        v = (il.w == e) ? pB.y : v;
        v = (cl0 == e) ? c0 : v;
        v = (cl1 == e) ? c1 : v;
        v = (cl2 == e) ? c2 : v;
        E[e] = v;
    }
    // packed E dwords; E[7]=1.0 pairs with b1 at A's k=7
    const uint32_t ep0 = pk_f16(E[0], E[1]);
    const uint32_t ep1 = pk_f16(E[2], E[3]);
    const uint32_t ep2 = pk_f16(E[4], E[5]);
    const uint32_t ep3 = pk_f16(E[6], 1.0f);

    // ---- layer-1 B-frags: E rows ct*16+lj pulled via shfl (zeros for k>=8) ----
    uint4 bfe[4];
#pragma unroll
    for (int ct = 0; ct < 4; ++ct) {
        const int src = ct * 16 + lj;
        const uint32_t s0 = (uint32_t)__shfl((int)ep0, src);
        const uint32_t s1 = (uint32_t)__shfl((int)ep1, src);
        const uint32_t s2 = (uint32_t)__shfl((int)ep2, src);
        const uint32_t s3 = (uint32_t)__shfl((int)ep3, src);
        bfe[ct].x = hi0 ? s0 : 0u;
        bfe[ct].y = hi0 ? s1 : 0u;
        bfe[ct].z = hi0 ? s2 : 0u;
        bfe[ct].w = hi0 ? s3 : 0u;
    }

    // ---- layer 1 via MFMA: 6 mt-tiles x 4 ct-tiles; ELU+pack -> Hs slots ----
    const uint32_t* w1a = (const uint32_t*)(wsf + WS_W1A);
    const int k0    = 4 * hi;                 // + mt*16 below
#pragma unroll
    for (int mt = 0; mt < 6; ++mt) {
        const uint4 au = *(const uint4*)(w1a + mt * 256 + lane * 4);
        const f16x8 afr = __builtin_bit_cast(f16x8, au);
        const int kk   = mt * 16 + k0;        // h1-index of c[0]
        const int ks   = kk >> 5;
        const int hi2  = (kk & 31) >> 3;
        const int dpair = (kk & 7) >> 1;      // 0 or 2
#pragma unroll
        for (int ct = 0; ct < 4; ++ct) {
            f32x4 c = (f32x4){0.f, 0.f, 0.f, 0.f};
            c = __builtin_amdgcn_mfma_f32_16x16x32_f16(
                afr, __builtin_bit_cast(f16x8, bfe[ct]), c, 0, 0, 0);
            const uint32_t d0 = pk_f16(elu_f(c[0]), elu_f(c[1]));
            const uint32_t d1 = pk_f16(elu_f(c[2]), elu_f(c[3]));
            const int slot = ((w * 3 + ks) * 4 + ct) * 64 + hi2 * 16 + lj;
            uint2 v2; v2.x = d0; v2.y = d1;
            *(uint2*)&Hs[slot * 8 + dpair * 2] = v2;   // 8B-aligned b64 write
        }
    }

    // ---- per-lane epilogue constants ----
    const float* B2V = wsf + WS_B2V;
    const float* W3V = wsf + WS_W3V;
    float b2j[6], w3j[6];
#pragma unroll
    for (int jt = 0; jt < 6; ++jt) {
        b2j[jt] = B2V[jt * 16 + lj];
        w3j[jt] = W3V[jt * 16 + lj];
    }
    const float B3v = wsf[WS_B3];

    // ---- layer 2+3, jt-streamed; A-frags re-read from LDS (same wave) ----
    const _Float16* w2f = (const _Float16*)(wsf + WS_W2F);
    f32x4 psum[4];
#pragma unroll
    for (int rt = 0; rt < 4; ++rt) psum[rt] = (f32x4){0.f, 0.f, 0.f, 0.f};

#pragma unroll
    for (int jt = 0; jt < 6; ++jt) {
        f32x4 acc[4];
#pragma unroll
        for (int rt = 0; rt < 4; ++rt)
            acc[rt] = (f32x4){b2j[jt], b2j[jt], b2j[jt], b2j[jt]};
#pragma unroll
        for (int ks = 0; ks < 3; ++ks) {
            const f16x8 bfr = *(const f16x8*)(w2f + (((ks * 6 + jt) * 64 + lane) << 3));
#pragma unroll
            for (int rt = 0; rt < 4; ++rt) {
                const f16x8 afr = *(const f16x8*)&Hs[(((w * 3 + ks) * 4 + rt) * 64 + lane) * 8];
                acc[rt] = __builtin_amdgcn_mfma_f32_16x16x32_f16(afr, bfr, acc[rt], 0, 0, 0);
            }
        }
        const float w3 = w3j[jt];
#pragma unroll
        for (int rt = 0; rt < 4; ++rt) {
            psum[rt][0] = __builtin_fmaf(elu_f(acc[rt][0]), w3, psum[rt][0]);
            psum[rt][1] = __builtin_fmaf(elu_f(acc[rt][1]), w3, psum[rt][1]);
            psum[rt][2] = __builtin_fmaf(elu_f(acc[rt][2]), w3, psum[rt][2]);
            psum[rt][3] = __builtin_fmaf(elu_f(acc[rt][3]), w3, psum[rt][3]);
        }
    }

    // ---- 16-lane shfl reduce + store (C layout: col=lj, row=4*lg+reg) ----
    const int rowbase = blockIdx.x * 256 + w * 64;
#pragma unroll
    for (int rt = 0; rt < 4; ++rt) {
        float p0 = psum[rt][0], p1 = psum[rt][1], p2 = psum[rt][2], p3 = psum[rt][3];
#pragma unroll
        for (int mask = 1; mask < 16; mask <<= 1) {
            p0 += __shfl_xor(p0, mask);
            p1 += __shfl_xor(p1, mask);
            p2 += __shfl_xor(p2, mask);
            p3 += __shfl_xor(p3, mask);
        }
        if (lj < 4) {
            const float v = (lj == 0) ? p0 : (lj == 1) ? p1 : (lj == 2) ? p2 : p3;
            out[rowbase + rt * 16 + 4 * hi + lj] = v + B3v;
        }
    }
}

extern "C" void kernel_launch(void* const* d_in, const int* in_sizes, int n_in,
                              void* d_out, int out_size, void* d_ws, size_t ws_size,
                              hipStream_t stream)
{
    const float* x          = (const float*)d_in[0];
    const float* controls   = (const float*)d_in[1];
    const float* W1         = (const float*)d_in[2];
    const float* b1         = (const float*)d_in[3];
    const float* W2         = (const float*)d_in[4];
    const float* b2         = (const float*)d_in[5];
    const float* W3         = (const float*)d_in[6];
    const float* b3         = (const float*)d_in[7];
    const int* inputs_list  = (const int*)d_in[8];
    const int* control_list = (const int*)d_in[9];
    float* out = (float*)d_out;
    float* wsf = (float*)d_ws;

    hipLaunchKernelGGL(prep_kernel, dim3(48), dim3(256), 0, stream,
                       W1, b1, W2, b2, W3, b3, wsf);
    hipLaunchKernelGGL(dnpu_main, dim3(4096), dim3(256), 0, stream,
                       x, controls, inputs_list, control_list, wsf, out);
}